// Round 1
// baseline (788.935 us; speedup 1.0000x reference)
//
#include <hip/hip_runtime.h>
#include <stddef.h>

// ---------------------------------------------------------------------------
// 2-layer GCN: h = relu(Agg(x@W1)+b1); h = relu(Agg(h@W2)+b2); out = meanpool
// Agg: symmetric-normalized (deg^-1/2) adjacency with self-loops, via dst-CSR
// built per-call (histogram -> scan -> scatter), pull-style (no f32 atomics).
// ---------------------------------------------------------------------------

#define F 128            // feature dim (IN=HID=OUT=128)
#define SCAN_E 1024      // elements per scan block (256 thr x 4)

// ---------------- CSR build ----------------

__global__ void hist_kernel(const int* __restrict__ ei, int* __restrict__ cnt, int e) {
    int i = blockIdx.x * 256 + threadIdx.x;
    if (i < e) atomicAdd(&cnt[ei[e + i]], 1);   // dst = ei[1][i]
}

__global__ void dis_kernel(const int* __restrict__ cnt, float* __restrict__ dis, int n) {
    int i = blockIdx.x * 256 + threadIdx.x;
    if (i < n) dis[i] = rsqrtf((float)(cnt[i] + 1));   // +1 self loop, deg>=1
}

// per-block exclusive scan (256 thr x 4 elems), block totals to blksum
__global__ void scan1_kernel(const int* __restrict__ cnt, int* __restrict__ rp,
                             int* __restrict__ blksum, int n) {
    int t = threadIdx.x;
    int base = blockIdx.x * SCAN_E + t * 4;
    int v[4];
#pragma unroll
    for (int j = 0; j < 4; ++j) v[j] = (base + j < n) ? cnt[base + j] : 0;
    int tsum = v[0] + v[1] + v[2] + v[3];

    int lane = t & 63, w = t >> 6;
    int x = tsum;
#pragma unroll
    for (int d = 1; d < 64; d <<= 1) {
        int y = __shfl_up(x, d);
        if (lane >= d) x += y;
    }
    __shared__ int wsum[4];
    if (lane == 63) wsum[w] = x;
    __syncthreads();
    int woff = 0;
    for (int k = 0; k < w; ++k) woff += wsum[k];
    int incl = x + woff;
    int run = incl - tsum;   // exclusive prefix for this thread
#pragma unroll
    for (int j = 0; j < 4; ++j) {
        if (base + j < n) rp[base + j] = run;
        run += v[j];
    }
    if (t == 255) blksum[blockIdx.x] = incl;
}

// single-thread scan of the (<=128) block sums; writes rp[n] = total
__global__ void scan2_kernel(const int* __restrict__ blksum, int* __restrict__ blkoff,
                             int nb, int* __restrict__ rp, int n) {
    if (threadIdx.x == 0 && blockIdx.x == 0) {
        int run = 0;
        for (int i = 0; i < nb; ++i) { blkoff[i] = run; run += blksum[i]; }
        rp[n] = run;
    }
}

__global__ void scan3_kernel(int* __restrict__ rp, int* __restrict__ pos,
                             const int* __restrict__ blkoff, int n) {
    int i = blockIdx.x * 256 + threadIdx.x;
    if (i < n) {
        int v = rp[i] + blkoff[i >> 10];
        rp[i] = v;
        pos[i] = v;
    }
}

__global__ void scatter_kernel(const int* __restrict__ ei, int* __restrict__ pos,
                               int* __restrict__ srcs, int e) {
    int i = blockIdx.x * 256 + threadIdx.x;
    if (i < e) {
        int s = ei[i];          // src
        int d = ei[e + i];      // dst
        int p = atomicAdd(&pos[d], 1);
        srcs[p] = s;
    }
}

// ---------------- GEMM: C[n,128] = A[n,128] @ W[128,128] (f32) -------------
// block: 256 thr, tile 64 rows x 128 cols, thread tile 8x4, K staged 32/step

__global__ __launch_bounds__(256) void gemm128_kernel(const float* __restrict__ A,
                                                      const float* __restrict__ W,
                                                      float* __restrict__ C, int n) {
    __shared__ float As[64][36];    // padded stride (144B, 16B-aligned)
    __shared__ float Bs[32][128];
    const int t = threadIdx.x;
    const int r0 = blockIdx.x * 64;
    const int colg = t & 31;   // cols 4*colg .. +3
    const int rowg = t >> 5;   // rows rowg*8 .. +7

    float4 acc[8];
#pragma unroll
    for (int i = 0; i < 8; ++i) acc[i] = make_float4(0.f, 0.f, 0.f, 0.f);

    const int la_r = t >> 3;         // 0..31
    const int la_c = (t & 7) * 4;    // 0,4..28
    const int lb_r = t >> 5;         // 0..7
    const int lb_c = (t & 31) * 4;   // 0..124

    for (int k0 = 0; k0 < 128; k0 += 32) {
#pragma unroll
        for (int p = 0; p < 2; ++p) {
            int r = la_r + p * 32;
            float4 v = make_float4(0.f, 0.f, 0.f, 0.f);
            if (r0 + r < n) v = *(const float4*)(A + (size_t)(r0 + r) * F + k0 + la_c);
            *(float4*)&As[r][la_c] = v;
        }
#pragma unroll
        for (int p = 0; p < 4; ++p) {
            int kk = lb_r + p * 8;
            *(float4*)&Bs[kk][lb_c] = *(const float4*)(W + (size_t)(k0 + kk) * F + lb_c);
        }
        __syncthreads();
#pragma unroll
        for (int kk4 = 0; kk4 < 32; kk4 += 4) {
            float4 a4[8], b4[4];
#pragma unroll
            for (int i = 0; i < 8; ++i) a4[i] = *(const float4*)&As[rowg * 8 + i][kk4];
#pragma unroll
            for (int u = 0; u < 4; ++u) b4[u] = *(const float4*)&Bs[kk4 + u][colg * 4];
#pragma unroll
            for (int u = 0; u < 4; ++u) {
#pragma unroll
                for (int i = 0; i < 8; ++i) {
                    float av = (u == 0) ? a4[i].x : (u == 1) ? a4[i].y
                             : (u == 2) ? a4[i].z : a4[i].w;
                    acc[i].x = fmaf(av, b4[u].x, acc[i].x);
                    acc[i].y = fmaf(av, b4[u].y, acc[i].y);
                    acc[i].z = fmaf(av, b4[u].z, acc[i].z);
                    acc[i].w = fmaf(av, b4[u].w, acc[i].w);
                }
            }
        }
        __syncthreads();
    }
#pragma unroll
    for (int i = 0; i < 8; ++i) {
        int r = r0 + rowg * 8 + i;
        if (r < n) *(float4*)(C + (size_t)r * F + colg * 4) = acc[i];
    }
}

// ---------------- pull aggregation + bias + relu ---------------------------
// one wave per node; lane owns cols {2*lane, 2*lane+1}

__global__ __launch_bounds__(256) void agg_kernel(const float* __restrict__ h,
                                                  const int* __restrict__ rp,
                                                  const int* __restrict__ srcs,
                                                  const float* __restrict__ dis,
                                                  const float* __restrict__ bias,
                                                  float* __restrict__ out, int n) {
    int node = blockIdx.x * 4 + (threadIdx.x >> 6);
    if (node >= n) return;
    int lane = threadIdx.x & 63;
    float di = dis[node];
    int beg = rp[node], end = rp[node + 1];
    const float2* __restrict__ h2 = (const float2*)h;
    float2 hv = h2[(size_t)node * 64 + lane];
    float w0 = di * di;                 // self-loop weight
    float ax = hv.x * w0, ay = hv.y * w0;
    for (int j = beg; j < end; ++j) {
        int s = srcs[j];
        float ws = dis[s] * di;
        float2 v = h2[(size_t)s * 64 + lane];
        ax = fmaf(ws, v.x, ax);
        ay = fmaf(ws, v.y, ay);
    }
    float2 b = ((const float2*)bias)[lane];
    ax = fmaxf(ax + b.x, 0.f);
    ay = fmaxf(ay + b.y, 0.f);
    ((float2*)out)[(size_t)node * 64 + lane] = make_float2(ax, ay);
}

// ---------------- global mean pool (batch is sorted) -----------------------

__global__ __launch_bounds__(128) void pool_kernel(const float* __restrict__ h,
                                                   const int* __restrict__ batch,
                                                   float* __restrict__ out, int n) {
    __shared__ int sb[2];
    int g = blockIdx.x;
    if (threadIdx.x < 2) {
        int target = g + (int)threadIdx.x;
        int lo = 0, hi = n;
        while (lo < hi) {
            int mid = (lo + hi) >> 1;
            if (batch[mid] < target) lo = mid + 1; else hi = mid;
        }
        sb[threadIdx.x] = lo;
    }
    __syncthreads();
    int start = sb[0], end = sb[1];
    int c = threadIdx.x;
    float s = 0.f;
    for (int i = start; i < end; ++i) s += h[(size_t)i * F + c];
    float cntf = (float)(end - start);
    out[g * F + c] = s / fmaxf(cntf, 1.f);
}

// ---------------------------------------------------------------------------

extern "C" void kernel_launch(void* const* d_in, const int* in_sizes, int n_in,
                              void* d_out, int out_size, void* d_ws, size_t ws_size,
                              hipStream_t stream) {
    const float* x     = (const float*)d_in[0];
    const int*   ei    = (const int*)d_in[1];
    const int*   batch = (const int*)d_in[2];
    const float* W1    = (const float*)d_in[3];
    const float* b1    = (const float*)d_in[4];
    const float* W2    = (const float*)d_in[5];
    const float* b2    = (const float*)d_in[6];
    float* out = (float*)d_out;

    const int n = in_sizes[0] / F;       // 100000
    const int e = in_sizes[1] / 2;       // 1600000
    const int g = out_size / F;          // 512
    const int nb = (n + SCAN_E - 1) / SCAN_E;

    char* ws = (char*)d_ws;
    size_t off = 0;
    auto alloc = [&](size_t bytes) -> char* {
        char* p = ws + off;
        off += (bytes + 255) & ~(size_t)255;
        return p;
    };
    float* dis   = (float*)alloc((size_t)n * 4);
    int*   cnt   = (int*)  alloc((size_t)n * 4);
    int*   rp    = (int*)  alloc((size_t)(n + 1) * 4);
    int*   pos   = (int*)  alloc((size_t)n * 4);
    int*   blks  = (int*)  alloc((size_t)nb * 4);
    int*   blko  = (int*)  alloc((size_t)nb * 4);
    int*   srcs  = (int*)  alloc((size_t)e * 4);
    float* hbuf  = (float*)alloc((size_t)n * F * 4);
    float* abuf  = (float*)alloc((size_t)n * F * 4);
    (void)ws_size;

    // --- CSR build + norm ---
    hipMemsetAsync(cnt, 0, (size_t)n * 4, stream);
    hist_kernel<<<(e + 255) / 256, 256, 0, stream>>>(ei, cnt, e);
    dis_kernel<<<(n + 255) / 256, 256, 0, stream>>>(cnt, dis, n);
    scan1_kernel<<<nb, 256, 0, stream>>>(cnt, rp, blks, n);
    scan2_kernel<<<1, 64, 0, stream>>>(blks, blko, nb, rp, n);
    scan3_kernel<<<(n + 255) / 256, 256, 0, stream>>>(rp, pos, blko, n);
    scatter_kernel<<<(e + 255) / 256, 256, 0, stream>>>(ei, pos, srcs, e);

    // --- layer 1 ---
    gemm128_kernel<<<(n + 63) / 64, 256, 0, stream>>>(x, W1, hbuf, n);
    agg_kernel<<<(n + 3) / 4, 256, 0, stream>>>(hbuf, rp, srcs, dis, b1, abuf, n);

    // --- layer 2 ---
    gemm128_kernel<<<(n + 63) / 64, 256, 0, stream>>>(abuf, W2, hbuf, n);
    agg_kernel<<<(n + 3) / 4, 256, 0, stream>>>(hbuf, rp, srcs, dis, b2, abuf, n);

    // --- pool ---
    pool_kernel<<<g, 128, 0, stream>>>(abuf, batch, out, n);
}

// Round 2
// 547.283 us; speedup vs baseline: 1.4416x; 1.4416x over previous
//
#include <hip/hip_runtime.h>
#include <stddef.h>

// ---------------------------------------------------------------------------
// 2-layer GCN, bf16 intermediates: h = relu(Agg(x@W1)+b1); h = relu(Agg(h@W2)+b2)
// out = global mean pool. Agg via per-call dst-CSR with precomputed edge
// weights (src, dis[src]*dis[dst]) packed as uint2. All accumulation in f32.
// ---------------------------------------------------------------------------

#define F 128
#define SCAN_E 1024

typedef unsigned int uint;
typedef unsigned short ushort;

__device__ __forceinline__ float bf_lo(uint v) { return __uint_as_float(v << 16); }
__device__ __forceinline__ float bf_hi(uint v) { return __uint_as_float(v & 0xffff0000u); }
__device__ __forceinline__ ushort f2bf(float f) {
    uint u = __float_as_uint(f);
    u += 0x7fffu + ((u >> 16) & 1u);   // round to nearest even
    return (ushort)(u >> 16);
}
__device__ __forceinline__ uint pack_bf2(float lo, float hi) {
    return (uint)f2bf(lo) | ((uint)f2bf(hi) << 16);
}

// ---------------- CSR build ----------------

__global__ void hist_kernel(const int* __restrict__ ei, int* __restrict__ cnt, int e) {
    int i = blockIdx.x * 256 + threadIdx.x;
    if (i < e) atomicAdd(&cnt[ei[e + i]], 1);
}

__global__ void dis_kernel(const int* __restrict__ cnt, float* __restrict__ dis, int n) {
    int i = blockIdx.x * 256 + threadIdx.x;
    if (i < n) dis[i] = rsqrtf((float)(cnt[i] + 1));
}

__global__ void scan1_kernel(const int* __restrict__ cnt, int* __restrict__ rp,
                             int* __restrict__ blksum, int n) {
    int t = threadIdx.x;
    int base = blockIdx.x * SCAN_E + t * 4;
    int v[4];
#pragma unroll
    for (int j = 0; j < 4; ++j) v[j] = (base + j < n) ? cnt[base + j] : 0;
    int tsum = v[0] + v[1] + v[2] + v[3];
    int lane = t & 63, w = t >> 6;
    int x = tsum;
#pragma unroll
    for (int d = 1; d < 64; d <<= 1) {
        int y = __shfl_up(x, d);
        if (lane >= d) x += y;
    }
    __shared__ int wsum[4];
    if (lane == 63) wsum[w] = x;
    __syncthreads();
    int woff = 0;
    for (int k = 0; k < w; ++k) woff += wsum[k];
    int incl = x + woff;
    int run = incl - tsum;
#pragma unroll
    for (int j = 0; j < 4; ++j) {
        if (base + j < n) rp[base + j] = run;
        run += v[j];
    }
    if (t == 255) blksum[blockIdx.x] = incl;
}

__global__ void scan2_kernel(const int* __restrict__ blksum, int* __restrict__ blkoff,
                             int nb, int* __restrict__ rp, int n) {
    if (threadIdx.x == 0 && blockIdx.x == 0) {
        int run = 0;
        for (int i = 0; i < nb; ++i) { blkoff[i] = run; run += blksum[i]; }
        rp[n] = run;
    }
}

__global__ void scan3_kernel(int* __restrict__ rp, int* __restrict__ pos,
                             const int* __restrict__ blkoff, int n) {
    int i = blockIdx.x * 256 + threadIdx.x;
    if (i < n) {
        int v = rp[i] + blkoff[i >> 10];
        rp[i] = v;
        pos[i] = v;
    }
}

// scatter + fuse per-edge weight dis[s]*dis[d]
__global__ void scatter_kernel(const int* __restrict__ ei, int* __restrict__ pos,
                               const float* __restrict__ dis, uint2* __restrict__ ew, int e) {
    int i = blockIdx.x * 256 + threadIdx.x;
    if (i < e) {
        int s = ei[i];
        int d = ei[e + i];
        float w = dis[s] * dis[d];
        int p = atomicAdd(&pos[d], 1);
        ew[p] = make_uint2((uint)s, __float_as_uint(w));
    }
}

// ---------------- GEMM: C[n,128](bf16) = A[n,128] @ W[128,128] -------------
// A is f32 (layer 1) or bf16 (layer 2). 256 thr, 64x128 tile, 8x4/thread.

template <bool BF16IN>
__global__ __launch_bounds__(256) void gemm128_kernel(const float* __restrict__ Af,
                                                      const uint* __restrict__ Ab,
                                                      const float* __restrict__ W,
                                                      ushort* __restrict__ C, int n) {
    __shared__ float As[64][36];
    __shared__ float Bs[32][128];
    const int t = threadIdx.x;
    const int r0 = blockIdx.x * 64;
    const int colg = t & 31;
    const int rowg = t >> 5;

    float4 acc[8];
#pragma unroll
    for (int i = 0; i < 8; ++i) acc[i] = make_float4(0.f, 0.f, 0.f, 0.f);

    const int la_r = t >> 3;
    const int la_c = (t & 7) * 4;
    const int lb_r = t >> 5;
    const int lb_c = (t & 31) * 4;

    for (int k0 = 0; k0 < 128; k0 += 32) {
#pragma unroll
        for (int p = 0; p < 2; ++p) {
            int r = la_r + p * 32;
            float4 v = make_float4(0.f, 0.f, 0.f, 0.f);
            if (r0 + r < n) {
                if (BF16IN) {
                    uint2 u = *(const uint2*)(Ab + ((size_t)(r0 + r) * F + k0 + la_c) / 2);
                    v = make_float4(bf_lo(u.x), bf_hi(u.x), bf_lo(u.y), bf_hi(u.y));
                } else {
                    v = *(const float4*)(Af + (size_t)(r0 + r) * F + k0 + la_c);
                }
            }
            *(float4*)&As[r][la_c] = v;
        }
#pragma unroll
        for (int p = 0; p < 4; ++p) {
            int kk = lb_r + p * 8;
            *(float4*)&Bs[kk][lb_c] = *(const float4*)(W + (size_t)(k0 + kk) * F + lb_c);
        }
        __syncthreads();
#pragma unroll
        for (int kk4 = 0; kk4 < 32; kk4 += 4) {
            float4 a4[8], b4[4];
#pragma unroll
            for (int i = 0; i < 8; ++i) a4[i] = *(const float4*)&As[rowg * 8 + i][kk4];
#pragma unroll
            for (int u = 0; u < 4; ++u) b4[u] = *(const float4*)&Bs[kk4 + u][colg * 4];
#pragma unroll
            for (int u = 0; u < 4; ++u) {
#pragma unroll
                for (int i = 0; i < 8; ++i) {
                    float av = (u == 0) ? a4[i].x : (u == 1) ? a4[i].y
                             : (u == 2) ? a4[i].z : a4[i].w;
                    acc[i].x = fmaf(av, b4[u].x, acc[i].x);
                    acc[i].y = fmaf(av, b4[u].y, acc[i].y);
                    acc[i].z = fmaf(av, b4[u].z, acc[i].z);
                    acc[i].w = fmaf(av, b4[u].w, acc[i].w);
                }
            }
        }
        __syncthreads();
    }
#pragma unroll
    for (int i = 0; i < 8; ++i) {
        int r = r0 + rowg * 8 + i;
        if (r < n) {
            ushort4 cu;
            cu.x = f2bf(acc[i].x);
            cu.y = f2bf(acc[i].y);
            cu.z = f2bf(acc[i].z);
            cu.w = f2bf(acc[i].w);
            *(ushort4*)(C + (size_t)r * F + colg * 4) = cu;
        }
    }
}

// ---------------- pull aggregation + bias + relu (bf16 in/out) -------------
// one wave per node; lane owns col pair {2*lane, 2*lane+1} (one uint)

__global__ __launch_bounds__(256) void agg_kernel(const uint* __restrict__ h2,
                                                  const int* __restrict__ rp,
                                                  const uint2* __restrict__ ew,
                                                  const float* __restrict__ dis,
                                                  const float* __restrict__ bias,
                                                  uint* __restrict__ out2, int n) {
    int node = blockIdx.x * 4 + (threadIdx.x >> 6);
    if (node >= n) return;
    int lane = threadIdx.x & 63;
    float di = dis[node];
    int beg = rp[node], end = rp[node + 1];
    uint hv = h2[((uint)node << 6) | lane];
    float w0 = di * di;
    float ax = w0 * bf_lo(hv);
    float ay = w0 * bf_hi(hv);
    int j = beg;
    for (; j + 2 <= end; j += 2) {
        uint2 e0 = ew[j];
        uint2 e1 = ew[j + 1];
        uint v0 = h2[(e0.x << 6) | lane];
        uint v1 = h2[(e1.x << 6) | lane];
        float wf0 = __uint_as_float(e0.y);
        float wf1 = __uint_as_float(e1.y);
        ax = fmaf(wf0, bf_lo(v0), ax);
        ay = fmaf(wf0, bf_hi(v0), ay);
        ax = fmaf(wf1, bf_lo(v1), ax);
        ay = fmaf(wf1, bf_hi(v1), ay);
    }
    if (j < end) {
        uint2 e0 = ew[j];
        uint v0 = h2[(e0.x << 6) | lane];
        float wf0 = __uint_as_float(e0.y);
        ax = fmaf(wf0, bf_lo(v0), ax);
        ay = fmaf(wf0, bf_hi(v0), ay);
    }
    float2 b = ((const float2*)bias)[lane];
    ax = fmaxf(ax + b.x, 0.f);
    ay = fmaxf(ay + b.y, 0.f);
    out2[((uint)node << 6) | lane] = pack_bf2(ax, ay);
}

// ---------------- global mean pool (batch sorted, bf16 in, f32 out) --------

__global__ __launch_bounds__(256) void pool_kernel(const uint* __restrict__ h2,
                                                   const int* __restrict__ batch,
                                                   float* __restrict__ out, int n) {
    __shared__ int sb[2];
    __shared__ float red[4][F];
    int g = blockIdx.x;
    int t = threadIdx.x;
    if (t < 2) {
        int target = g + t;
        int lo = 0, hi = n;
        while (lo < hi) {
            int mid = (lo + hi) >> 1;
            if (batch[mid] < target) lo = mid + 1; else hi = mid;
        }
        sb[t] = lo;
    }
    __syncthreads();
    int start = sb[0], end = sb[1];
    int lane = t & 63, w = t >> 6;
    float sx = 0.f, sy = 0.f;
    for (int i = start + w; i < end; i += 4) {
        uint v = h2[((uint)i << 6) | lane];
        sx += bf_lo(v);
        sy += bf_hi(v);
    }
    red[w][lane * 2] = sx;
    red[w][lane * 2 + 1] = sy;
    __syncthreads();
    if (w == 0) {
        float s0 = red[0][lane * 2] + red[1][lane * 2] + red[2][lane * 2] + red[3][lane * 2];
        float s1 = red[0][lane * 2 + 1] + red[1][lane * 2 + 1] + red[2][lane * 2 + 1] + red[3][lane * 2 + 1];
        float cntf = (float)(end - start);
        float inv = 1.f / fmaxf(cntf, 1.f);
        out[(size_t)g * F + lane * 2]     = s0 * inv;
        out[(size_t)g * F + lane * 2 + 1] = s1 * inv;
    }
}

// ---------------------------------------------------------------------------

extern "C" void kernel_launch(void* const* d_in, const int* in_sizes, int n_in,
                              void* d_out, int out_size, void* d_ws, size_t ws_size,
                              hipStream_t stream) {
    const float* x     = (const float*)d_in[0];
    const int*   ei    = (const int*)d_in[1];
    const int*   batch = (const int*)d_in[2];
    const float* W1    = (const float*)d_in[3];
    const float* b1    = (const float*)d_in[4];
    const float* W2    = (const float*)d_in[5];
    const float* b2    = (const float*)d_in[6];
    float* out = (float*)d_out;

    const int n = in_sizes[0] / F;
    const int e = in_sizes[1] / 2;
    const int g = out_size / F;
    const int nb = (n + SCAN_E - 1) / SCAN_E;

    char* ws = (char*)d_ws;
    size_t off = 0;
    auto alloc = [&](size_t bytes) -> char* {
        char* p = ws + off;
        off += (bytes + 255) & ~(size_t)255;
        return p;
    };
    float* dis  = (float*)alloc((size_t)n * 4);
    int*   cnt  = (int*)  alloc((size_t)n * 4);
    int*   rp   = (int*)  alloc((size_t)(n + 1) * 4);
    int*   pos  = (int*)  alloc((size_t)n * 4);
    int*   blks = (int*)  alloc((size_t)nb * 4);
    int*   blko = (int*)  alloc((size_t)nb * 4);
    uint2* ew   = (uint2*)alloc((size_t)e * 8);
    uint*  hbuf = (uint*) alloc((size_t)n * F * 2);   // bf16 x2 per uint
    uint*  abuf = (uint*) alloc((size_t)n * F * 2);
    (void)ws_size;

    // --- CSR build + norm + edge weights ---
    hipMemsetAsync(cnt, 0, (size_t)n * 4, stream);
    hist_kernel<<<(e + 255) / 256, 256, 0, stream>>>(ei, cnt, e);
    dis_kernel<<<(n + 255) / 256, 256, 0, stream>>>(cnt, dis, n);
    scan1_kernel<<<nb, 256, 0, stream>>>(cnt, rp, blks, n);
    scan2_kernel<<<1, 64, 0, stream>>>(blks, blko, nb, rp, n);
    scan3_kernel<<<(n + 255) / 256, 256, 0, stream>>>(rp, pos, blko, n);
    scatter_kernel<<<(e + 255) / 256, 256, 0, stream>>>(ei, pos, dis, ew, e);

    // --- layer 1 ---
    gemm128_kernel<false><<<(n + 63) / 64, 256, 0, stream>>>(x, nullptr, W1, (ushort*)hbuf, n);
    agg_kernel<<<(n + 3) / 4, 256, 0, stream>>>(hbuf, rp, ew, dis, b1, abuf, n);

    // --- layer 2 ---
    gemm128_kernel<true><<<(n + 63) / 64, 256, 0, stream>>>(nullptr, abuf, W2, (ushort*)hbuf, n);
    agg_kernel<<<(n + 3) / 4, 256, 0, stream>>>(hbuf, rp, ew, dis, b2, abuf, n);

    // --- pool ---
    pool_kernel<<<g, 256, 0, stream>>>(abuf, batch, out, n);
}

// Round 3
// 538.359 us; speedup vs baseline: 1.4654x; 1.0166x over previous
//
#include <hip/hip_runtime.h>
#include <stddef.h>

// ---------------------------------------------------------------------------
// 2-layer GCN, bf16 intermediates + MFMA GEMMs.
// h = relu(Agg(x@W1)+b1); h = relu(Agg(h@W2)+b2); out = mean pool per graph.
// GEMM: C = A * W via mfma_f32_16x16x32_bf16 with W pre-split into
// bf16 hi+lo (W ~= hi + lo) to suppress correlated weight-rounding error.
// Agg: dst-CSR (hist->scan->scatter), pull, f32 accumulate, bias+relu fused.
// ---------------------------------------------------------------------------

#define F 128
#define SCAN_E 1024

typedef unsigned int uint;
typedef unsigned short ushort;
typedef __attribute__((ext_vector_type(8))) short s16x8;   // 8 bf16
typedef __attribute__((ext_vector_type(4))) float f32x4;

__device__ __forceinline__ float bf_lo(uint v) { return __uint_as_float(v << 16); }
__device__ __forceinline__ float bf_hi(uint v) { return __uint_as_float(v & 0xffff0000u); }
__device__ __forceinline__ ushort f2bf(float f) {
    uint u = __float_as_uint(f);
    u += 0x7fffu + ((u >> 16) & 1u);   // RNE
    return (ushort)(u >> 16);
}
__device__ __forceinline__ uint pack_bf2(float lo, float hi) {
    return (uint)f2bf(lo) | ((uint)f2bf(hi) << 16);
}

// ---------------- CSR build ----------------

__global__ void hist_kernel(const int* __restrict__ ei, int* __restrict__ cnt, int e) {
    int i = blockIdx.x * 256 + threadIdx.x;
    if (i < e) atomicAdd(&cnt[ei[e + i]], 1);
}

__global__ void dis_kernel(const int* __restrict__ cnt, float* __restrict__ dis, int n) {
    int i = blockIdx.x * 256 + threadIdx.x;
    if (i < n) dis[i] = rsqrtf((float)(cnt[i] + 1));
}

__global__ void scan1_kernel(const int* __restrict__ cnt, int* __restrict__ rp,
                             int* __restrict__ blksum, int n) {
    int t = threadIdx.x;
    int base = blockIdx.x * SCAN_E + t * 4;
    int v[4];
#pragma unroll
    for (int j = 0; j < 4; ++j) v[j] = (base + j < n) ? cnt[base + j] : 0;
    int tsum = v[0] + v[1] + v[2] + v[3];
    int lane = t & 63, w = t >> 6;
    int x = tsum;
#pragma unroll
    for (int d = 1; d < 64; d <<= 1) {
        int y = __shfl_up(x, d);
        if (lane >= d) x += y;
    }
    __shared__ int wsum[4];
    if (lane == 63) wsum[w] = x;
    __syncthreads();
    int woff = 0;
    for (int k = 0; k < w; ++k) woff += wsum[k];
    int incl = x + woff;
    int run = incl - tsum;
#pragma unroll
    for (int j = 0; j < 4; ++j) {
        if (base + j < n) rp[base + j] = run;
        run += v[j];
    }
    if (t == 255) blksum[blockIdx.x] = incl;
}

// parallel scan of block sums (nb <= 128)
__global__ void scan2_kernel(const int* __restrict__ blksum, int* __restrict__ blkoff,
                             int nb, int* __restrict__ rp, int n) {
    __shared__ int s[128];
    int t = threadIdx.x;
    int v = (t < nb) ? blksum[t] : 0;
    s[t] = v;
    __syncthreads();
    for (int d = 1; d < 128; d <<= 1) {
        int y = (t >= d) ? s[t - d] : 0;
        __syncthreads();
        s[t] += y;
        __syncthreads();
    }
    if (t < nb) blkoff[t] = s[t] - v;
    if (t == 127) rp[n] = s[127];
}

__global__ void scan3_kernel(int* __restrict__ rp, int* __restrict__ pos,
                             const int* __restrict__ blkoff, int n) {
    int i = blockIdx.x * 256 + threadIdx.x;
    if (i < n) {
        int v = rp[i] + blkoff[i >> 10];
        rp[i] = v;
        pos[i] = v;
    }
}

__global__ void scatter_kernel(const int* __restrict__ ei, int* __restrict__ pos,
                               int* __restrict__ srcs, int e) {
    int i = blockIdx.x * 256 + threadIdx.x;
    if (i < e) {
        int s = ei[i];
        int d = ei[e + i];
        int p = atomicAdd(&pos[d], 1);
        srcs[p] = s;
    }
}

// ---------------- W prep: Wt[m][part][col][k] bf16, hi + residual-lo -------

__global__ void wprep_kernel(const float* __restrict__ W1, const float* __restrict__ W2,
                             ushort* __restrict__ wt) {
    int idx = blockIdx.x * 256 + threadIdx.x;     // 2 * 128 * 128
    if (idx >= 2 * F * F) return;
    int m = idx >> 14;
    int c = (idx >> 7) & 127;   // col of W (row of Wt)
    int r = idx & 127;          // k
    const float* W = m ? W2 : W1;
    float w = W[r * F + c];
    ushort hi = f2bf(w);
    float whi = __uint_as_float((uint)hi << 16);
    ushort lo = f2bf(w - whi);
    // layout: [m][part][c][r]
    wt[((m * 2 + 0) * F + c) * F + r] = hi;
    wt[((m * 2 + 1) * F + c) * F + r] = lo;
}

// ---------------- MFMA GEMM: C[n,128](bf16) = A[n,128] @ W ------------------
// block: 256 thr = 4 waves; tile 128 rows x 128 cols; wave w -> rows w*32..+31
// A staged in LDS (bf16, XOR-swizzled 16B granules); W from global (L1/L2-hot)
// mfma C-layout: row=(lane>>4)*4+reg, col=lane&15  [m89/m91 verified]
// A/B frag: lane holds op[lane&15][(lane>>4)*8 + j], j=0..7 (16B contiguous)

template <bool F32IN>
__global__ __launch_bounds__(256) void gemm_mfma_kernel(const float* __restrict__ Af,
                                                        const uint* __restrict__ Ab,
                                                        const ushort* __restrict__ wt,
                                                        ushort* __restrict__ C, int n) {
    __shared__ uint4 As4[2048];          // 128 rows x 16 granules(16B) = 32 KB
    const int t = threadIdx.x;
    const int w = t >> 6;
    const int lane = t & 63;
    const int r0 = blockIdx.x * 128;

    // ---- stage A tile (bf16) into swizzled LDS ----
#pragma unroll
    for (int p = 0; p < 8; ++p) {
        int g = p * 256 + t;
        int row = g >> 4;
        int c8 = g & 15;
        uint4 v = make_uint4(0u, 0u, 0u, 0u);
        if (r0 + row < n) {
            if (F32IN) {
                const float* a = Af + (size_t)(r0 + row) * F + c8 * 8;
                float4 f0 = *(const float4*)a;
                float4 f1 = *(const float4*)(a + 4);
                v.x = pack_bf2(f0.x, f0.y);
                v.y = pack_bf2(f0.z, f0.w);
                v.z = pack_bf2(f1.x, f1.y);
                v.w = pack_bf2(f1.z, f1.w);
            } else {
                v = *(const uint4*)(Ab + ((size_t)(r0 + row) * F + c8 * 8) / 2);
            }
        }
        As4[row * 16 + (c8 ^ (row & 7))] = v;
    }
    __syncthreads();

    const s16x8* As8 = (const s16x8*)As4;
    const uint4* Bh = (const uint4*)wt;               // [part][col][k] granules
    const uint4* Bl = Bh + F * 16;                    // lo part

    f32x4 acc[2][8];
#pragma unroll
    for (int i = 0; i < 2; ++i)
#pragma unroll
        for (int c = 0; c < 8; ++c) acc[i][c] = (f32x4){0.f, 0.f, 0.f, 0.f};

    const int kg = lane >> 4;          // k-group 0..3
    const int lr = lane & 15;

#pragma unroll
    for (int ks = 0; ks < 4; ++ks) {
        s16x8 a0, a1;
        {
            int row = w * 32 + lr;
            a0 = As8[row * 16 + ((ks * 4 + kg) ^ (row & 7))];
            row += 16;
            a1 = As8[row * 16 + ((ks * 4 + kg) ^ (row & 7))];
        }
#pragma unroll
        for (int c = 0; c < 8; ++c) {
            int col = c * 16 + lr;
            int gidx = col * 16 + ks * 4 + kg;
            uint4 bhu = Bh[gidx];
            uint4 blu = Bl[gidx];
            s16x8 bh = *(const s16x8*)&bhu;
            s16x8 bl = *(const s16x8*)&blu;
            acc[0][c] = __builtin_amdgcn_mfma_f32_16x16x32_bf16(a0, bh, acc[0][c], 0, 0, 0);
            acc[0][c] = __builtin_amdgcn_mfma_f32_16x16x32_bf16(a0, bl, acc[0][c], 0, 0, 0);
            acc[1][c] = __builtin_amdgcn_mfma_f32_16x16x32_bf16(a1, bh, acc[1][c], 0, 0, 0);
            acc[1][c] = __builtin_amdgcn_mfma_f32_16x16x32_bf16(a1, bl, acc[1][c], 0, 0, 0);
        }
    }

    // ---- epilogue: acc -> LDS (bf16) -> coalesced global ----
    __syncthreads();
    ushort* Cs = (ushort*)As4;
#pragma unroll
    for (int i = 0; i < 2; ++i)
#pragma unroll
        for (int c = 0; c < 8; ++c)
#pragma unroll
            for (int reg = 0; reg < 4; ++reg) {
                int row = w * 32 + i * 16 + (lane >> 4) * 4 + reg;
                int col = c * 16 + lr;
                Cs[row * F + col] = f2bf(acc[i][c][reg]);
            }
    __syncthreads();
#pragma unroll
    for (int p = 0; p < 8; ++p) {
        int g = p * 256 + t;
        int row = g >> 4;
        int c8 = g & 15;
        if (r0 + row < n)
            *(uint4*)(C + (size_t)(r0 + row) * F + c8 * 8) = As4[g];
    }
}

// ---------------- pull aggregation + bias + relu (bf16 in/out) -------------

__global__ __launch_bounds__(256) void agg_kernel(const uint* __restrict__ h2,
                                                  const int* __restrict__ rp,
                                                  const int* __restrict__ srcs,
                                                  const float* __restrict__ dis,
                                                  const float* __restrict__ bias,
                                                  uint* __restrict__ out2, int n) {
    int node = blockIdx.x * 4 + (threadIdx.x >> 6);
    if (node >= n) return;
    int lane = threadIdx.x & 63;
    float di = dis[node];
    int beg = rp[node], end = rp[node + 1];
    uint hv = h2[((uint)node << 6) | lane];
    float w0 = di * di;
    float ax = w0 * bf_lo(hv);
    float ay = w0 * bf_hi(hv);
    int j = beg;
    for (; j + 4 <= end; j += 4) {
        int s0 = srcs[j], s1 = srcs[j + 1], s2 = srcs[j + 2], s3 = srcs[j + 3];
        float d0 = dis[s0], d1 = dis[s1], d2 = dis[s2], d3 = dis[s3];
        uint v0 = h2[((uint)s0 << 6) | lane];
        uint v1 = h2[((uint)s1 << 6) | lane];
        uint v2 = h2[((uint)s2 << 6) | lane];
        uint v3 = h2[((uint)s3 << 6) | lane];
        float w0e = d0 * di, w1e = d1 * di, w2e = d2 * di, w3e = d3 * di;
        ax = fmaf(w0e, bf_lo(v0), ax); ay = fmaf(w0e, bf_hi(v0), ay);
        ax = fmaf(w1e, bf_lo(v1), ax); ay = fmaf(w1e, bf_hi(v1), ay);
        ax = fmaf(w2e, bf_lo(v2), ax); ay = fmaf(w2e, bf_hi(v2), ay);
        ax = fmaf(w3e, bf_lo(v3), ax); ay = fmaf(w3e, bf_hi(v3), ay);
    }
    for (; j < end; ++j) {
        int s0 = srcs[j];
        float w0e = dis[s0] * di;
        uint v0 = h2[((uint)s0 << 6) | lane];
        ax = fmaf(w0e, bf_lo(v0), ax);
        ay = fmaf(w0e, bf_hi(v0), ay);
    }
    float2 b = ((const float2*)bias)[lane];
    ax = fmaxf(ax + b.x, 0.f);
    ay = fmaxf(ay + b.y, 0.f);
    out2[((uint)node << 6) | lane] = pack_bf2(ax, ay);
}

// ---------------- global mean pool (batch sorted, bf16 in, f32 out) --------

__global__ __launch_bounds__(256) void pool_kernel(const uint* __restrict__ h2,
                                                   const int* __restrict__ batch,
                                                   float* __restrict__ out, int n) {
    __shared__ int sb[2];
    __shared__ float red[4][F];
    int g = blockIdx.x;
    int t = threadIdx.x;
    if (t < 2) {
        int target = g + t;
        int lo = 0, hi = n;
        while (lo < hi) {
            int mid = (lo + hi) >> 1;
            if (batch[mid] < target) lo = mid + 1; else hi = mid;
        }
        sb[t] = lo;
    }
    __syncthreads();
    int start = sb[0], end = sb[1];
    int lane = t & 63, w = t >> 6;
    float sx = 0.f, sy = 0.f;
    for (int i = start + w; i < end; i += 4) {
        uint v = h2[((uint)i << 6) | lane];
        sx += bf_lo(v);
        sy += bf_hi(v);
    }
    red[w][lane * 2] = sx;
    red[w][lane * 2 + 1] = sy;
    __syncthreads();
    if (w == 0) {
        float s0 = red[0][lane * 2] + red[1][lane * 2] + red[2][lane * 2] + red[3][lane * 2];
        float s1 = red[0][lane * 2 + 1] + red[1][lane * 2 + 1] + red[2][lane * 2 + 1] + red[3][lane * 2 + 1];
        float inv = 1.f / fmaxf((float)(end - start), 1.f);
        out[(size_t)g * F + lane * 2]     = s0 * inv;
        out[(size_t)g * F + lane * 2 + 1] = s1 * inv;
    }
}

// ---------------------------------------------------------------------------

extern "C" void kernel_launch(void* const* d_in, const int* in_sizes, int n_in,
                              void* d_out, int out_size, void* d_ws, size_t ws_size,
                              hipStream_t stream) {
    const float* x     = (const float*)d_in[0];
    const int*   ei    = (const int*)d_in[1];
    const int*   batch = (const int*)d_in[2];
    const float* W1    = (const float*)d_in[3];
    const float* b1    = (const float*)d_in[4];
    const float* W2    = (const float*)d_in[5];
    const float* b2    = (const float*)d_in[6];
    float* out = (float*)d_out;

    const int n = in_sizes[0] / F;
    const int e = in_sizes[1] / 2;
    const int g = out_size / F;
    const int nb = (n + SCAN_E - 1) / SCAN_E;

    char* ws = (char*)d_ws;
    size_t off = 0;
    auto alloc = [&](size_t bytes) -> char* {
        char* p = ws + off;
        off += (bytes + 255) & ~(size_t)255;
        return p;
    };
    float*  dis  = (float*)alloc((size_t)n * 4);
    int*    cnt  = (int*)  alloc((size_t)n * 4);
    int*    rp   = (int*)  alloc((size_t)(n + 1) * 4);
    int*    pos  = (int*)  alloc((size_t)n * 4);
    int*    blks = (int*)  alloc((size_t)nb * 4);
    int*    blko = (int*)  alloc((size_t)nb * 4);
    int*    srcs = (int*)  alloc((size_t)e * 4);
    ushort* wt   = (ushort*)alloc((size_t)4 * F * F * 2);  // [m][part][c][k]
    uint*   hbuf = (uint*) alloc((size_t)n * F * 2);
    uint*   abuf = (uint*) alloc((size_t)n * F * 2);
    (void)ws_size;

    // --- CSR build + norm + W prep ---
    hipMemsetAsync(cnt, 0, (size_t)n * 4, stream);
    hist_kernel<<<(e + 255) / 256, 256, 0, stream>>>(ei, cnt, e);
    wprep_kernel<<<(2 * F * F + 255) / 256, 256, 0, stream>>>(W1, W2, wt);
    dis_kernel<<<(n + 255) / 256, 256, 0, stream>>>(cnt, dis, n);
    scan1_kernel<<<nb, 256, 0, stream>>>(cnt, rp, blks, n);
    scan2_kernel<<<1, 128, 0, stream>>>(blks, blko, nb, rp, n);
    scan3_kernel<<<(n + 255) / 256, 256, 0, stream>>>(rp, pos, blko, n);
    scatter_kernel<<<(e + 255) / 256, 256, 0, stream>>>(ei, pos, srcs, e);

    const int gblk = (n + 127) / 128;
    // --- layer 1 ---
    gemm_mfma_kernel<true><<<gblk, 256, 0, stream>>>(x, nullptr, wt, (ushort*)hbuf, n);
    agg_kernel<<<(n + 3) / 4, 256, 0, stream>>>(hbuf, rp, srcs, dis, b1, abuf, n);
    // --- layer 2 ---
    gemm_mfma_kernel<false><<<gblk, 256, 0, stream>>>(nullptr, abuf, wt + 2 * F * F, (ushort*)hbuf, n);
    agg_kernel<<<(n + 3) / 4, 256, 0, stream>>>(hbuf, rp, srcs, dis, b2, abuf, n);
    // --- pool ---
    pool_kernel<<<g, 256, 0, stream>>>(abuf, batch, out, n);
}

// Round 4
// 381.370 us; speedup vs baseline: 2.0687x; 1.4116x over previous
//
#include <hip/hip_runtime.h>
#include <stddef.h>

// ---------------------------------------------------------------------------
// 2-layer GCN, bf16 intermediates + MFMA GEMMs + bucketed CSR build.
// h = relu(Agg(x@W1)+b1); h = relu(Agg(h@W2)+b2); out = mean pool per graph.
// CSR build: bucket by dst>>9 (LDS multisplit, coalesced runs), then per-bucket
// fine hist/scan/scatter with LDS atomics only; random writes stay L2-local.
// ---------------------------------------------------------------------------

#define F 128
#define EB 4096          // edges per passB block
#define BSH 9            // bucket = dst >> 9 (512 nodes per bucket)

typedef unsigned int uint;
typedef unsigned short ushort;
typedef __attribute__((ext_vector_type(8))) short s16x8;   // 8 bf16
typedef __attribute__((ext_vector_type(4))) float f32x4;

__device__ __forceinline__ float bf_lo(uint v) { return __uint_as_float(v << 16); }
__device__ __forceinline__ float bf_hi(uint v) { return __uint_as_float(v & 0xffff0000u); }
__device__ __forceinline__ ushort f2bf(float f) {
    uint u = __float_as_uint(f);
    u += 0x7fffu + ((u >> 16) & 1u);   // RNE
    return (ushort)(u >> 16);
}
__device__ __forceinline__ uint pack_bf2(float lo, float hi) {
    return (uint)f2bf(lo) | ((uint)f2bf(hi) << 16);
}

// inclusive Hillis-Steele scan over 256 entries (all 256 threads must call)
__device__ __forceinline__ int scan256_incl(int* s, int t, int v) {
    s[t] = v;
    __syncthreads();
#pragma unroll
    for (int d = 1; d < 256; d <<= 1) {
        int y = (t >= d) ? s[t - d] : 0;
        __syncthreads();
        s[t] += y;
        __syncthreads();
    }
    return s[t];
}

// ---------------- pass A: coarse bucket histogram --------------------------

__global__ __launch_bounds__(256) void passA_kernel(const int* __restrict__ ei,
                                                    int* __restrict__ bucket_cnt,
                                                    int e, int nbuc) {
    __shared__ int h[256];
    int t = threadIdx.x;
    h[t] = 0;
    __syncthreads();
    for (int i = blockIdx.x * 256 + t; i < e; i += gridDim.x * 256)
        atomicAdd(&h[ei[e + i] >> BSH], 1);
    __syncthreads();
    if (t < nbuc && h[t]) atomicAdd(&bucket_cnt[t], h[t]);
}

// ---------------- scan of bucket counts ------------------------------------

__global__ __launch_bounds__(256) void scanb_kernel(const int* __restrict__ bucket_cnt,
                                                    int* __restrict__ bucket_base,
                                                    int* __restrict__ gcur, int nbuc) {
    __shared__ int aux[256];
    int t = threadIdx.x;
    int v = (t < nbuc) ? bucket_cnt[t] : 0;
    int incl = scan256_incl(aux, t, v);
    int base = incl - v;
    bucket_base[t] = base;
    gcur[t] = base;
    if (t == nbuc - 1) bucket_base[nbuc] = incl;
}

// ---------------- pass B: bucketed edge dump (LDS multisplit) --------------

__global__ __launch_bounds__(256) void passB_kernel(const int* __restrict__ ei,
                                                    int* __restrict__ gcur,
                                                    uint2* __restrict__ ebuf, int e) {
    __shared__ uint2 stage[EB];
    __shared__ int h[256], start[256], cur[256], claim[256], aux[256];
    int t = threadIdx.x;
    h[t] = 0;
    __syncthreads();
    int base = blockIdx.x * EB;
    int s_r[16], d_r[16];
#pragma unroll
    for (int k = 0; k < 16; ++k) {
        int i = base + k * 256 + t;
        int sv = -1, dv = 0;
        if (i < e) {
            sv = ei[i];
            dv = ei[e + i];
            atomicAdd(&h[dv >> BSH], 1);
        }
        s_r[k] = sv; d_r[k] = dv;
    }
    __syncthreads();
    int hv = h[t];
    int incl = scan256_incl(aux, t, hv);
    start[t] = incl - hv;
    cur[t]   = incl - hv;
    claim[t] = (hv > 0) ? atomicAdd(&gcur[t], hv) : 0;
    __syncthreads();
#pragma unroll
    for (int k = 0; k < 16; ++k) {
        if (s_r[k] >= 0) {
            int b = d_r[k] >> BSH;
            int r = atomicAdd(&cur[b], 1);
            stage[r] = make_uint2((uint)s_r[k], (uint)d_r[k]);
        }
    }
    __syncthreads();
    int valid = min(EB, e - base);
#pragma unroll
    for (int k = 0; k < 16; ++k) {
        int idx = k * 256 + t;
        if (idx < valid) {
            uint2 ed = stage[idx];
            int b = (int)(ed.y >> BSH);
            ebuf[claim[b] + (idx - start[b])] = ed;
        }
    }
}

// ---------------- pass C1: per-bucket fine hist -> rp, dis -----------------

__global__ __launch_bounds__(256) void passC1_kernel(const uint2* __restrict__ ebuf,
                                                     const int* __restrict__ bucket_base,
                                                     int* __restrict__ rp,
                                                     float* __restrict__ dis, int n) {
    __shared__ int h[512];
    __shared__ int aux[256];
    int t = threadIdx.x, b = blockIdx.x;
    int v0 = b << BSH;
    h[t] = 0; h[t + 256] = 0;
    __syncthreads();
    int ebeg = bucket_base[b], eend = bucket_base[b + 1];
    for (int i = ebeg + t; i < eend; i += 256)
        atomicAdd(&h[(int)ebuf[i].y - v0], 1);
    __syncthreads();
#pragma unroll
    for (int k = 0; k < 2; ++k) {
        int v = v0 + t + k * 256;
        if (v < n) dis[v] = rsqrtf((float)(h[t + k * 256] + 1));
    }
    int p = h[2 * t] + h[2 * t + 1];
    int incl = scan256_incl(aux, t, p);
    int ex = incl - p;
    int v = v0 + 2 * t;
    if (v <= n)     rp[v]     = ebeg + ex;
    if (v + 1 <= n) rp[v + 1] = ebeg + ex + h[2 * t];
}

// ---------------- pass C2: per-bucket scatter -> ew=(src, norm) ------------

__global__ __launch_bounds__(256) void passC2_kernel(const uint2* __restrict__ ebuf,
                                                     const int* __restrict__ bucket_base,
                                                     const int* __restrict__ rp,
                                                     const float* __restrict__ dis,
                                                     uint2* __restrict__ ew, int n) {
    __shared__ int cur[512];
    __shared__ float dl[512];
    int t = threadIdx.x, b = blockIdx.x;
    int v0 = b << BSH;
#pragma unroll
    for (int k = 0; k < 2; ++k) {
        int idx = t + k * 256, v = v0 + idx;
        cur[idx] = (v < n) ? rp[v] : 0;
        dl[idx]  = (v < n) ? dis[v] : 0.f;
    }
    __syncthreads();
    int ebeg = bucket_base[b], eend = bucket_base[b + 1];
    for (int i = ebeg + t; i < eend; i += 256) {
        uint2 ed = ebuf[i];
        int s = (int)ed.x, d = (int)ed.y - v0;
        float w = dis[s] * dl[d];
        int p = atomicAdd(&cur[d], 1);
        ew[p] = make_uint2(ed.x, __float_as_uint(w));
    }
}

// ---------------- W prep: Wt[m][part][col][k] bf16, hi + residual-lo -------

__global__ void wprep_kernel(const float* __restrict__ W1, const float* __restrict__ W2,
                             ushort* __restrict__ wt) {
    int idx = blockIdx.x * 256 + threadIdx.x;     // 2 * 128 * 128
    if (idx >= 2 * F * F) return;
    int m = idx >> 14;
    int c = (idx >> 7) & 127;
    int r = idx & 127;
    const float* W = m ? W2 : W1;
    float w = W[r * F + c];
    ushort hi = f2bf(w);
    float whi = __uint_as_float((uint)hi << 16);
    ushort lo = f2bf(w - whi);
    wt[((m * 2 + 0) * F + c) * F + r] = hi;
    wt[((m * 2 + 1) * F + c) * F + r] = lo;
}

// ---------------- MFMA GEMM: C[n,128](bf16) = A[n,128] @ W ------------------

template <bool F32IN>
__global__ __launch_bounds__(256) void gemm_mfma_kernel(const float* __restrict__ Af,
                                                        const uint* __restrict__ Ab,
                                                        const ushort* __restrict__ wt,
                                                        ushort* __restrict__ C, int n) {
    __shared__ uint4 As4[2048];          // 128 rows x 16 granules(16B) = 32 KB
    const int t = threadIdx.x;
    const int w = t >> 6;
    const int lane = t & 63;
    const int r0 = blockIdx.x * 128;

#pragma unroll
    for (int p = 0; p < 8; ++p) {
        int g = p * 256 + t;
        int row = g >> 4;
        int c8 = g & 15;
        uint4 v = make_uint4(0u, 0u, 0u, 0u);
        if (r0 + row < n) {
            if (F32IN) {
                const float* a = Af + (size_t)(r0 + row) * F + c8 * 8;
                float4 f0 = *(const float4*)a;
                float4 f1 = *(const float4*)(a + 4);
                v.x = pack_bf2(f0.x, f0.y);
                v.y = pack_bf2(f0.z, f0.w);
                v.z = pack_bf2(f1.x, f1.y);
                v.w = pack_bf2(f1.z, f1.w);
            } else {
                v = *(const uint4*)(Ab + ((size_t)(r0 + row) * F + c8 * 8) / 2);
            }
        }
        As4[row * 16 + (c8 ^ (row & 7))] = v;
    }
    __syncthreads();

    const s16x8* As8 = (const s16x8*)As4;
    const uint4* Bh = (const uint4*)wt;
    const uint4* Bl = Bh + F * 16;

    f32x4 acc[2][8];
#pragma unroll
    for (int i = 0; i < 2; ++i)
#pragma unroll
        for (int c = 0; c < 8; ++c) acc[i][c] = (f32x4){0.f, 0.f, 0.f, 0.f};

    const int kg = lane >> 4;
    const int lr = lane & 15;

#pragma unroll
    for (int ks = 0; ks < 4; ++ks) {
        s16x8 a0, a1;
        {
            int row = w * 32 + lr;
            a0 = As8[row * 16 + ((ks * 4 + kg) ^ (row & 7))];
            row += 16;
            a1 = As8[row * 16 + ((ks * 4 + kg) ^ (row & 7))];
        }
#pragma unroll
        for (int c = 0; c < 8; ++c) {
            int col = c * 16 + lr;
            int gidx = col * 16 + ks * 4 + kg;
            uint4 bhu = Bh[gidx];
            uint4 blu = Bl[gidx];
            s16x8 bh = *(const s16x8*)&bhu;
            s16x8 bl = *(const s16x8*)&blu;
            acc[0][c] = __builtin_amdgcn_mfma_f32_16x16x32_bf16(a0, bh, acc[0][c], 0, 0, 0);
            acc[0][c] = __builtin_amdgcn_mfma_f32_16x16x32_bf16(a0, bl, acc[0][c], 0, 0, 0);
            acc[1][c] = __builtin_amdgcn_mfma_f32_16x16x32_bf16(a1, bh, acc[1][c], 0, 0, 0);
            acc[1][c] = __builtin_amdgcn_mfma_f32_16x16x32_bf16(a1, bl, acc[1][c], 0, 0, 0);
        }
    }

    __syncthreads();
    ushort* Cs = (ushort*)As4;
#pragma unroll
    for (int i = 0; i < 2; ++i)
#pragma unroll
        for (int c = 0; c < 8; ++c)
#pragma unroll
            for (int reg = 0; reg < 4; ++reg) {
                int row = w * 32 + i * 16 + (lane >> 4) * 4 + reg;
                int col = c * 16 + lr;
                Cs[row * F + col] = f2bf(acc[i][c][reg]);
            }
    __syncthreads();
#pragma unroll
    for (int p = 0; p < 8; ++p) {
        int g = p * 256 + t;
        int row = g >> 4;
        int c8 = g & 15;
        if (r0 + row < n)
            *(uint4*)(C + (size_t)(r0 + row) * F + c8 * 8) = As4[g];
    }
}

// ---------------- pull aggregation + bias + relu (bf16 in/out) -------------
// one wave per node; lane owns col pair {2*lane, 2*lane+1}; 8-wide unroll

__global__ __launch_bounds__(256) void agg_kernel(const uint* __restrict__ h2,
                                                  const int* __restrict__ rp,
                                                  const uint2* __restrict__ ew,
                                                  const float* __restrict__ dis,
                                                  const float* __restrict__ bias,
                                                  uint* __restrict__ out2, int n) {
    int wid = __builtin_amdgcn_readfirstlane(threadIdx.x >> 6);
    int node = blockIdx.x * 4 + wid;
    if (node >= n) return;
    int lane = threadIdx.x & 63;
    float di = dis[node];
    int beg = rp[node], end = rp[node + 1];
    uint hv = h2[((uint)node << 6) | lane];
    float w0 = di * di;
    float ax = w0 * bf_lo(hv);
    float ay = w0 * bf_hi(hv);
    int j = beg;
    for (; j + 8 <= end; j += 8) {
        uint2 E0 = ew[j],     E1 = ew[j + 1], E2 = ew[j + 2], E3 = ew[j + 3];
        uint2 E4 = ew[j + 4], E5 = ew[j + 5], E6 = ew[j + 6], E7 = ew[j + 7];
        uint v0 = h2[(E0.x << 6) | lane];
        uint v1 = h2[(E1.x << 6) | lane];
        uint v2 = h2[(E2.x << 6) | lane];
        uint v3 = h2[(E3.x << 6) | lane];
        uint v4 = h2[(E4.x << 6) | lane];
        uint v5 = h2[(E5.x << 6) | lane];
        uint v6 = h2[(E6.x << 6) | lane];
        uint v7 = h2[(E7.x << 6) | lane];
        float w0e = __uint_as_float(E0.y), w1e = __uint_as_float(E1.y);
        float w2e = __uint_as_float(E2.y), w3e = __uint_as_float(E3.y);
        float w4e = __uint_as_float(E4.y), w5e = __uint_as_float(E5.y);
        float w6e = __uint_as_float(E6.y), w7e = __uint_as_float(E7.y);
        ax = fmaf(w0e, bf_lo(v0), ax); ay = fmaf(w0e, bf_hi(v0), ay);
        ax = fmaf(w1e, bf_lo(v1), ax); ay = fmaf(w1e, bf_hi(v1), ay);
        ax = fmaf(w2e, bf_lo(v2), ax); ay = fmaf(w2e, bf_hi(v2), ay);
        ax = fmaf(w3e, bf_lo(v3), ax); ay = fmaf(w3e, bf_hi(v3), ay);
        ax = fmaf(w4e, bf_lo(v4), ax); ay = fmaf(w4e, bf_hi(v4), ay);
        ax = fmaf(w5e, bf_lo(v5), ax); ay = fmaf(w5e, bf_hi(v5), ay);
        ax = fmaf(w6e, bf_lo(v6), ax); ay = fmaf(w6e, bf_hi(v6), ay);
        ax = fmaf(w7e, bf_lo(v7), ax); ay = fmaf(w7e, bf_hi(v7), ay);
    }
    for (; j < end; ++j) {
        uint2 E0 = ew[j];
        uint v0 = h2[(E0.x << 6) | lane];
        float w0e = __uint_as_float(E0.y);
        ax = fmaf(w0e, bf_lo(v0), ax);
        ay = fmaf(w0e, bf_hi(v0), ay);
    }
    float2 b = ((const float2*)bias)[lane];
    ax = fmaxf(ax + b.x, 0.f);
    ay = fmaxf(ay + b.y, 0.f);
    out2[((uint)node << 6) | lane] = pack_bf2(ax, ay);
}

// ---------------- global mean pool (batch sorted, bf16 in, f32 out) --------

__global__ __launch_bounds__(256) void pool_kernel(const uint* __restrict__ h2,
                                                   const int* __restrict__ batch,
                                                   float* __restrict__ out, int n) {
    __shared__ int sb[2];
    __shared__ float red[4][F];
    int g = blockIdx.x;
    int t = threadIdx.x;
    if (t < 2) {
        int target = g + t;
        int lo = 0, hi = n;
        while (lo < hi) {
            int mid = (lo + hi) >> 1;
            if (batch[mid] < target) lo = mid + 1; else hi = mid;
        }
        sb[t] = lo;
    }
    __syncthreads();
    int start = sb[0], end = sb[1];
    int lane = t & 63, w = t >> 6;
    float sx = 0.f, sy = 0.f;
    for (int i = start + w; i < end; i += 4) {
        uint v = h2[((uint)i << 6) | lane];
        sx += bf_lo(v);
        sy += bf_hi(v);
    }
    red[w][lane * 2] = sx;
    red[w][lane * 2 + 1] = sy;
    __syncthreads();
    if (w == 0) {
        float s0 = red[0][lane * 2] + red[1][lane * 2] + red[2][lane * 2] + red[3][lane * 2];
        float s1 = red[0][lane * 2 + 1] + red[1][lane * 2 + 1] + red[2][lane * 2 + 1] + red[3][lane * 2 + 1];
        float inv = 1.f / fmaxf((float)(end - start), 1.f);
        out[(size_t)g * F + lane * 2]     = s0 * inv;
        out[(size_t)g * F + lane * 2 + 1] = s1 * inv;
    }
}

// ---------------------------------------------------------------------------

extern "C" void kernel_launch(void* const* d_in, const int* in_sizes, int n_in,
                              void* d_out, int out_size, void* d_ws, size_t ws_size,
                              hipStream_t stream) {
    const float* x     = (const float*)d_in[0];
    const int*   ei    = (const int*)d_in[1];
    const int*   batch = (const int*)d_in[2];
    const float* W1    = (const float*)d_in[3];
    const float* b1    = (const float*)d_in[4];
    const float* W2    = (const float*)d_in[5];
    const float* b2    = (const float*)d_in[6];
    float* out = (float*)d_out;

    const int n = in_sizes[0] / F;       // 100000
    const int e = in_sizes[1] / 2;       // 1600000
    const int g = out_size / F;          // 512
    const int nbuc = (n + (1 << BSH) - 1) >> BSH;   // 196

    char* ws = (char*)d_ws;
    size_t off = 0;
    auto alloc = [&](size_t bytes) -> char* {
        char* p = ws + off;
        off += (bytes + 255) & ~(size_t)255;
        return p;
    };
    float*  dis   = (float*)alloc((size_t)n * 4);
    int*    rp    = (int*)  alloc((size_t)(n + 1) * 4);
    int*    bcnt  = (int*)  alloc(256 * 4);
    int*    bbase = (int*)  alloc(257 * 4);
    int*    gcur  = (int*)  alloc(256 * 4);
    uint2*  ebuf  = (uint2*)alloc((size_t)e * 8);
    uint2*  ew    = (uint2*)alloc((size_t)e * 8);
    ushort* wt    = (ushort*)alloc((size_t)4 * F * F * 2);
    uint*   hbuf  = (uint*) alloc((size_t)n * F * 2);
    uint*   abuf  = (uint*) alloc((size_t)n * F * 2);
    (void)ws_size;

    // --- CSR build (bucketed) + W prep ---
    hipMemsetAsync(bcnt, 0, 256 * 4, stream);
    wprep_kernel<<<(2 * F * F + 255) / 256, 256, 0, stream>>>(W1, W2, wt);
    passA_kernel<<<256, 256, 0, stream>>>(ei, bcnt, e, nbuc);
    scanb_kernel<<<1, 256, 0, stream>>>(bcnt, bbase, gcur, nbuc);
    passB_kernel<<<(e + EB - 1) / EB, 256, 0, stream>>>(ei, gcur, ebuf, e);
    passC1_kernel<<<nbuc, 256, 0, stream>>>(ebuf, bbase, rp, dis, n);
    passC2_kernel<<<nbuc, 256, 0, stream>>>(ebuf, bbase, rp, dis, ew, n);

    const int gblk = (n + 127) / 128;
    // --- layer 1 ---
    gemm_mfma_kernel<true><<<gblk, 256, 0, stream>>>(x, nullptr, wt, (ushort*)hbuf, n);
    agg_kernel<<<(n + 3) / 4, 256, 0, stream>>>(hbuf, rp, ew, dis, b1, abuf, n);
    // --- layer 2 ---
    gemm_mfma_kernel<false><<<gblk, 256, 0, stream>>>(nullptr, abuf, wt + 2 * F * F, (ushort*)hbuf, n);
    agg_kernel<<<(n + 3) / 4, 256, 0, stream>>>(hbuf, rp, ew, dis, b2, abuf, n);
    // --- pool ---
    pool_kernel<<<g, 256, 0, stream>>>(abuf, batch, out, n);
}